// Round 1
// baseline (34999.222 us; speedup 1.0000x reference)
//
#include <hip/hip_runtime.h>
#include <math.h>

#define VV 8192
#define CC 512
#define TT 1024
#define NH 16
#define NL 12
#define HSZ 32
#define FFD 2048
#define BBATCH 8
#define MROWS (BBATCH*TT)   // 8192

// ---------------- embedding: x = tok[idx] + lab[idxl] + pos[t] ----------------
__global__ __launch_bounds__(128) void k_embed(const int* __restrict__ idx,
                                               const int* __restrict__ idxl,
                                               const float* __restrict__ tok,
                                               const float* __restrict__ pos,
                                               const float* __restrict__ lab,
                                               float* __restrict__ x) {
    int row = blockIdx.x;            // 0..8191  (b*T + t)
    int t = row & (TT - 1);
    int c = threadIdx.x * 4;         // 128 threads * 4 = 512
    int ti = idx[row], li = idxl[row];
    float4 a = *(const float4*)(tok + (size_t)ti * CC + c);
    float4 b = *(const float4*)(lab + (size_t)li * CC + c);
    float4 p = *(const float4*)(pos + (size_t)t * CC + c);
    float4 r;
    r.x = a.x + b.x + p.x; r.y = a.y + b.y + p.y;
    r.z = a.z + b.z + p.z; r.w = a.w + b.w + p.w;
    *(float4*)(x + (size_t)row * CC + c) = r;
}

// ---------------- layernorm: one wave per row of 512 ----------------
__global__ __launch_bounds__(256) void k_ln(const float* __restrict__ x,
                                            const float* __restrict__ g,
                                            const float* __restrict__ b,
                                            float* __restrict__ y) {
    int wave = threadIdx.x >> 6;
    int lane = threadIdx.x & 63;
    int row = blockIdx.x * 4 + wave;
    const float* xr = x + (size_t)row * CC + lane * 8;
    float v[8];
    *(float4*)(v)     = *(const float4*)(xr);
    *(float4*)(v + 4) = *(const float4*)(xr + 4);
    float s = 0.f, sq = 0.f;
#pragma unroll
    for (int i = 0; i < 8; i++) { s += v[i]; sq += v[i] * v[i]; }
#pragma unroll
    for (int off = 32; off; off >>= 1) {
        s  += __shfl_xor(s,  off);
        sq += __shfl_xor(sq, off);
    }
    float mean = s * (1.f / CC);
    float var  = sq * (1.f / CC) - mean * mean;
    float inv  = rsqrtf(var + 1e-5f);
    float gv[8], bv[8];
    *(float4*)(gv)     = *(const float4*)(g + lane * 8);
    *(float4*)(gv + 4) = *(const float4*)(g + lane * 8 + 4);
    *(float4*)(bv)     = *(const float4*)(b + lane * 8);
    *(float4*)(bv + 4) = *(const float4*)(b + lane * 8 + 4);
    float o[8];
#pragma unroll
    for (int i = 0; i < 8; i++) o[i] = (v[i] - mean) * inv * gv[i] + bv[i];
    float* yr = y + (size_t)row * CC + lane * 8;
    *(float4*)(yr)     = *(const float4*)(o);
    *(float4*)(yr + 4) = *(const float4*)(o + 4);
}

// ---------------- fp32 GEMM: C[M,N] = A[M,K] @ B + bias (opt relu / opt add) --
// LAYB==0: B row-major [K,N].  LAYB==1: qkv layout, col n=(h*32+d) at
//          B[h*(K*32) + k*32 + d].
template<int RELU, int ADD, int LAYB>
__global__ __launch_bounds__(256) void k_gemm(const float* __restrict__ A,
                                              const float* __restrict__ B,
                                              const float* __restrict__ bias,
                                              float* __restrict__ Cout,
                                              int Mi, int Ni, int Ki) {
    __shared__ float As[16][68];   // [k][m], padded
    __shared__ float Bs[16][68];   // [k][n], padded
    int tid = threadIdx.x;
    int bm = blockIdx.y * 64;
    int bn = blockIdx.x * 64;
    int tx = tid & 15, ty = tid >> 4;
    int arow = tid >> 2, akq = tid & 3;    // A staging: row 0..63, k-quad 0..3
    int brow = tid >> 4, bc4 = tid & 15;   // B staging: k 0..15, col-quad 0..15
    float c[4][4] = {};
    for (int k0 = 0; k0 < Ki; k0 += 16) {
        float4 av = *(const float4*)(A + (size_t)(bm + arow) * Ki + k0 + akq * 4);
        float4 bvld;
        if (LAYB == 0) {
            bvld = *(const float4*)(B + (size_t)(k0 + brow) * Ni + bn + bc4 * 4);
        } else {
            int n = bn + bc4 * 4;
            bvld = *(const float4*)(B + (size_t)(n >> 5) * (Ki * 32)
                                      + (size_t)(k0 + brow) * 32 + (n & 31));
        }
        __syncthreads();
        As[akq * 4 + 0][arow] = av.x;
        As[akq * 4 + 1][arow] = av.y;
        As[akq * 4 + 2][arow] = av.z;
        As[akq * 4 + 3][arow] = av.w;
        *(float4*)(&Bs[brow][bc4 * 4]) = bvld;
        __syncthreads();
#pragma unroll
        for (int kk = 0; kk < 16; kk++) {
            float a[4], bb[4];
            *(float4*)a  = *(const float4*)(&As[kk][ty * 4]);
            *(float4*)bb = *(const float4*)(&Bs[kk][tx * 4]);
#pragma unroll
            for (int i = 0; i < 4; i++)
#pragma unroll
                for (int j = 0; j < 4; j++)
                    c[i][j] += a[i] * bb[j];
        }
    }
    float bv[4] = {0.f, 0.f, 0.f, 0.f};
    if (bias) *(float4*)bv = *(const float4*)(bias + bn + tx * 4);
#pragma unroll
    for (int i = 0; i < 4; i++) {
        float* cp = Cout + (size_t)(bm + ty * 4 + i) * Ni + bn + tx * 4;
        float r[4];
#pragma unroll
        for (int j = 0; j < 4; j++) {
            r[j] = c[i][j] + bv[j];
            if (RELU) r[j] = fmaxf(r[j], 0.f);
        }
        if (ADD) {
            float old[4];
            *(float4*)old = *(const float4*)cp;
#pragma unroll
            for (int j = 0; j < 4; j++) r[j] += old[j];
        }
        *(float4*)cp = *(const float4*)r;
    }
}

// ---------------- attention: one wave per (b,h,t) query row, online softmax ---
__global__ __launch_bounds__(256) void k_attn(const float* __restrict__ q,
                                              const float* __restrict__ k,
                                              const float* __restrict__ v,
                                              float* __restrict__ o) {
    int wave = threadIdx.x >> 6;
    int lane = threadIdx.x & 63;
    int gid = blockIdx.x;            // 0..32767
    int tb = gid & 255;              // T/4 = 256
    int bh = gid >> 8;               // 0..127
    int b = bh >> 4, h = bh & 15;
    int t = tb * 4 + wave;
    const float* qrow = q + (size_t)(b * TT + t) * CC + h * HSZ;
    float qr[32];
#pragma unroll
    for (int d = 0; d < 32; d += 4) {
        float4 qq = *(const float4*)(qrow + d);
        qr[d] = qq.x; qr[d + 1] = qq.y; qr[d + 2] = qq.z; qr[d + 3] = qq.w;
    }
    const float scale = 0.1767766952966369f;  // 1/sqrt(32)
    float m = -1e30f, l = 0.f;
    float acc[32];
#pragma unroll
    for (int d = 0; d < 32; d++) acc[d] = 0.f;
    for (int s = lane; s <= t; s += 64) {
        const float* krow = k + (size_t)(b * TT + s) * CC + h * HSZ;
        float dot = 0.f;
#pragma unroll
        for (int d = 0; d < 32; d += 4) {
            float4 kk = *(const float4*)(krow + d);
            dot += qr[d] * kk.x + qr[d + 1] * kk.y + qr[d + 2] * kk.z + qr[d + 3] * kk.w;
        }
        float xv = dot * scale;
        float mn = fmaxf(m, xv);
        float corr = __expf(m - mn);
        float p = __expf(xv - mn);
        l = l * corr + p;
        const float* vrow = v + (size_t)(b * TT + s) * CC + h * HSZ;
#pragma unroll
        for (int d = 0; d < 32; d += 4) {
            float4 vv = *(const float4*)(vrow + d);
            acc[d]     = acc[d]     * corr + p * vv.x;
            acc[d + 1] = acc[d + 1] * corr + p * vv.y;
            acc[d + 2] = acc[d + 2] * corr + p * vv.z;
            acc[d + 3] = acc[d + 3] * corr + p * vv.w;
        }
        m = mn;
    }
    // merge 64 lanes
#pragma unroll
    for (int off = 32; off; off >>= 1) {
        float m2 = __shfl_xor(m, off);
        float l2 = __shfl_xor(l, off);
        float mn = fmaxf(m, m2);
        float c1 = __expf(m - mn), c2 = __expf(m2 - mn);
        l = l * c1 + l2 * c2;
#pragma unroll
        for (int d = 0; d < 32; d++) {
            float a2 = __shfl_xor(acc[d], off);
            acc[d] = acc[d] * c1 + a2 * c2;
        }
        m = mn;
    }
    float invl = 1.f / l;
    if (lane == 0) {
        float* orow = o + (size_t)(b * TT + t) * CC + h * HSZ;
#pragma unroll
        for (int d = 0; d < 32; d += 4) {
            float4 r;
            r.x = acc[d] * invl; r.y = acc[d + 1] * invl;
            r.z = acc[d + 2] * invl; r.w = acc[d + 3] * invl;
            *(float4*)(orow + d) = r;
        }
    }
}

// ---------------- loss ----------------
__global__ void k_zero(float* p) { *p = 0.f; }

__global__ __launch_bounds__(256) void k_loss(const float* __restrict__ logits,
                                              const int* __restrict__ targets,
                                              float* __restrict__ loss) {
    int row = blockIdx.x;
    const float* lr = logits + (size_t)row * VV;
    int tid = threadIdx.x;
    float m = -1e30f, s = 0.f;
    for (int j = tid * 4; j < VV; j += 1024) {
        float4 xv = *(const float4*)(lr + j);
        float xs[4] = {xv.x, xv.y, xv.z, xv.w};
#pragma unroll
        for (int u = 0; u < 4; u++) {
            float mn = fmaxf(m, xs[u]);
            s = s * __expf(m - mn) + __expf(xs[u] - mn);
            m = mn;
        }
    }
#pragma unroll
    for (int off = 32; off; off >>= 1) {
        float m2 = __shfl_xor(m, off);
        float s2 = __shfl_xor(s, off);
        float mn = fmaxf(m, m2);
        s = s * __expf(m - mn) + s2 * __expf(m2 - mn);
        m = mn;
    }
    __shared__ float sm[4], ss[4];
    int wave = tid >> 6, lane = tid & 63;
    if (lane == 0) { sm[wave] = m; ss[wave] = s; }
    __syncthreads();
    if (tid == 0) {
        float M = fmaxf(fmaxf(sm[0], sm[1]), fmaxf(sm[2], sm[3]));
        float S = ss[0] * __expf(sm[0] - M) + ss[1] * __expf(sm[1] - M)
                + ss[2] * __expf(sm[2] - M) + ss[3] * __expf(sm[3] - M);
        float lt = lr[targets[row]];
        atomicAdd(loss, -(lt - M - logf(S)) * (1.0f / (float)MROWS));
    }
}

// ---------------- orchestration ----------------
extern "C" void kernel_launch(void* const* d_in, const int* in_sizes, int n_in,
                              void* d_out, int out_size, void* d_ws, size_t ws_size,
                              hipStream_t stream) {
    const int*   idx   = (const int*)d_in[0];
    const int*   idxl  = (const int*)d_in[1];
    const int*   tgt   = (const int*)d_in[2];
    const float* tok   = (const float*)d_in[3];
    const float* pos   = (const float*)d_in[4];
    const float* lab   = (const float*)d_in[5];
    const float* Wq    = (const float*)d_in[6];
    const float* Wk    = (const float*)d_in[7];
    const float* Wv    = (const float*)d_in[8];
    const float* Wo    = (const float*)d_in[9];
    const float* bo    = (const float*)d_in[10];
    const float* ln1g  = (const float*)d_in[11];
    const float* ln1b  = (const float*)d_in[12];
    const float* W1    = (const float*)d_in[13];
    const float* b1    = (const float*)d_in[14];
    const float* W2    = (const float*)d_in[15];
    const float* b2    = (const float*)d_in[16];
    const float* ln2g  = (const float*)d_in[17];
    const float* ln2b  = (const float*)d_in[18];
    const float* lnfg  = (const float*)d_in[19];
    const float* lnfb  = (const float*)d_in[20];
    const float* Wlm   = (const float*)d_in[21];
    const float* blm   = (const float*)d_in[22];
    float* out = (float*)d_out;
    float* ws  = (float*)d_ws;

    const size_t NTOK = (size_t)MROWS * CC;   // 4,194,304
    float* x  = ws;
    float* h  = x  + NTOK;
    float* qb = h  + NTOK;
    float* kb = qb + NTOK;
    float* vb = kb + NTOK;
    float* ob = vb + NTOK;
    float* ff = ob + NTOK;                    // 8192*2048

    dim3 blk(256);
    dim3 gs_sq(CC / 64, MROWS / 64);          // 8  x 128
    dim3 gs_ff(FFD / 64, MROWS / 64);         // 32 x 128
    dim3 gs_lm(VV / 64, MROWS / 64);          // 128 x 128

    k_embed<<<MROWS, 128, 0, stream>>>(idx, idxl, tok, pos, lab, x);

    for (int l = 0; l < NL; l++) {
        k_ln<<<MROWS / 4, blk, 0, stream>>>(x, ln1g + l * CC, ln1b + l * CC, h);
        const size_t wqkv = (size_t)l * NH * CC * HSZ;
        k_gemm<0, 0, 1><<<gs_sq, blk, 0, stream>>>(h, Wq + wqkv, nullptr, qb, MROWS, CC, CC);
        k_gemm<0, 0, 1><<<gs_sq, blk, 0, stream>>>(h, Wk + wqkv, nullptr, kb, MROWS, CC, CC);
        k_gemm<0, 0, 1><<<gs_sq, blk, 0, stream>>>(h, Wv + wqkv, nullptr, vb, MROWS, CC, CC);
        k_attn<<<BBATCH * NH * (TT / 4), blk, 0, stream>>>(qb, kb, vb, ob);
        k_gemm<0, 1, 0><<<gs_sq, blk, 0, stream>>>(ob, Wo + (size_t)l * CC * CC,
                                                   bo + l * CC, x, MROWS, CC, CC);
        k_ln<<<MROWS / 4, blk, 0, stream>>>(x, ln2g + l * CC, ln2b + l * CC, h);
        k_gemm<1, 0, 0><<<gs_ff, blk, 0, stream>>>(h, W1 + (size_t)l * CC * FFD,
                                                   b1 + l * FFD, ff, MROWS, FFD, CC);
        k_gemm<0, 1, 0><<<gs_sq, blk, 0, stream>>>(ff, W2 + (size_t)l * FFD * CC,
                                                   b2 + l * CC, x, MROWS, CC, FFD);
    }

    k_ln<<<MROWS / 4, blk, 0, stream>>>(x, lnfg, lnfb, h);
    k_gemm<0, 0, 0><<<gs_lm, blk, 0, stream>>>(h, Wlm, blm, out, MROWS, VV, CC);

    float* loss_p = out + (size_t)MROWS * VV;
    k_zero<<<1, 1, 0, stream>>>(loss_p);
    k_loss<<<MROWS, blk, 0, stream>>>(out, tgt, loss_p);
}

// Round 2
// 17229.543 us; speedup vs baseline: 2.0313x; 2.0313x over previous
//
#include <hip/hip_runtime.h>
#include <math.h>

#define VV 8192
#define CC 512
#define TT 1024
#define NH 16
#define NL 12
#define HSZ 32
#define FFD 2048
#define BBATCH 8
#define MROWS (BBATCH*TT)   // 8192

// ---------------- embedding: x = tok[idx] + lab[idxl] + pos[t] ----------------
__global__ __launch_bounds__(128) void k_embed(const int* __restrict__ idx,
                                               const int* __restrict__ idxl,
                                               const float* __restrict__ tok,
                                               const float* __restrict__ pos,
                                               const float* __restrict__ lab,
                                               float* __restrict__ x) {
    int row = blockIdx.x;            // 0..8191  (b*T + t)
    int t = row & (TT - 1);
    int c = threadIdx.x * 4;         // 128 threads * 4 = 512
    int ti = idx[row], li = idxl[row];
    float4 a = *(const float4*)(tok + (size_t)ti * CC + c);
    float4 b = *(const float4*)(lab + (size_t)li * CC + c);
    float4 p = *(const float4*)(pos + (size_t)t * CC + c);
    float4 r;
    r.x = a.x + b.x + p.x; r.y = a.y + b.y + p.y;
    r.z = a.z + b.z + p.z; r.w = a.w + b.w + p.w;
    *(float4*)(x + (size_t)row * CC + c) = r;
}

// ---------------- layernorm: one wave per row of 512 ----------------
__global__ __launch_bounds__(256) void k_ln(const float* __restrict__ x,
                                            const float* __restrict__ g,
                                            const float* __restrict__ b,
                                            float* __restrict__ y) {
    int wave = threadIdx.x >> 6;
    int lane = threadIdx.x & 63;
    int row = blockIdx.x * 4 + wave;
    const float* xr = x + (size_t)row * CC + lane * 8;
    float v[8];
    *(float4*)(v)     = *(const float4*)(xr);
    *(float4*)(v + 4) = *(const float4*)(xr + 4);
    float s = 0.f, sq = 0.f;
#pragma unroll
    for (int i = 0; i < 8; i++) { s += v[i]; sq += v[i] * v[i]; }
#pragma unroll
    for (int off = 32; off; off >>= 1) {
        s  += __shfl_xor(s,  off);
        sq += __shfl_xor(sq, off);
    }
    float mean = s * (1.f / CC);
    float var  = sq * (1.f / CC) - mean * mean;
    float inv  = rsqrtf(var + 1e-5f);
    float gv[8], bv[8];
    *(float4*)(gv)     = *(const float4*)(g + lane * 8);
    *(float4*)(gv + 4) = *(const float4*)(g + lane * 8 + 4);
    *(float4*)(bv)     = *(const float4*)(b + lane * 8);
    *(float4*)(bv + 4) = *(const float4*)(b + lane * 8 + 4);
    float o[8];
#pragma unroll
    for (int i = 0; i < 8; i++) o[i] = (v[i] - mean) * inv * gv[i] + bv[i];
    float* yr = y + (size_t)row * CC + lane * 8;
    *(float4*)(yr)     = *(const float4*)(o);
    *(float4*)(yr + 4) = *(const float4*)(o + 4);
}

// ---------------- fp32 GEMM: C[M,N] = A[M,K] @ B + bias (opt relu / opt add) --
// LAYB==0: B row-major [K,N].  LAYB==1: qkv layout, col n=(h*32+d) at
//          B[h*(K*32) + k*32 + d].
template<int RELU, int ADD, int LAYB>
__global__ __launch_bounds__(256) void k_gemm(const float* __restrict__ A,
                                              const float* __restrict__ B,
                                              const float* __restrict__ bias,
                                              float* __restrict__ Cout,
                                              int Mi, int Ni, int Ki) {
    __shared__ float As[16][68];   // [k][m], padded
    __shared__ float Bs[16][68];   // [k][n], padded
    int tid = threadIdx.x;
    int bm = blockIdx.y * 64;
    int bn = blockIdx.x * 64;
    int tx = tid & 15, ty = tid >> 4;
    int arow = tid >> 2, akq = tid & 3;    // A staging: row 0..63, k-quad 0..3
    int brow = tid >> 4, bc4 = tid & 15;   // B staging: k 0..15, col-quad 0..15
    float c[4][4] = {};
    for (int k0 = 0; k0 < Ki; k0 += 16) {
        float4 av = *(const float4*)(A + (size_t)(bm + arow) * Ki + k0 + akq * 4);
        float4 bvld;
        if (LAYB == 0) {
            bvld = *(const float4*)(B + (size_t)(k0 + brow) * Ni + bn + bc4 * 4);
        } else {
            int n = bn + bc4 * 4;
            bvld = *(const float4*)(B + (size_t)(n >> 5) * (Ki * 32)
                                      + (size_t)(k0 + brow) * 32 + (n & 31));
        }
        __syncthreads();
        As[akq * 4 + 0][arow] = av.x;
        As[akq * 4 + 1][arow] = av.y;
        As[akq * 4 + 2][arow] = av.z;
        As[akq * 4 + 3][arow] = av.w;
        *(float4*)(&Bs[brow][bc4 * 4]) = bvld;
        __syncthreads();
#pragma unroll
        for (int kk = 0; kk < 16; kk++) {
            float a[4], bb[4];
            *(float4*)a  = *(const float4*)(&As[kk][ty * 4]);
            *(float4*)bb = *(const float4*)(&Bs[kk][tx * 4]);
#pragma unroll
            for (int i = 0; i < 4; i++)
#pragma unroll
                for (int j = 0; j < 4; j++)
                    c[i][j] += a[i] * bb[j];
        }
    }
    float bv[4] = {0.f, 0.f, 0.f, 0.f};
    if (bias) *(float4*)bv = *(const float4*)(bias + bn + tx * 4);
#pragma unroll
    for (int i = 0; i < 4; i++) {
        float* cp = Cout + (size_t)(bm + ty * 4 + i) * Ni + bn + tx * 4;
        float r[4];
#pragma unroll
        for (int j = 0; j < 4; j++) {
            r[j] = c[i][j] + bv[j];
            if (RELU) r[j] = fmaxf(r[j], 0.f);
        }
        if (ADD) {
            float old[4];
            *(float4*)old = *(const float4*)cp;
#pragma unroll
            for (int j = 0; j < 4; j++) r[j] += old[j];
        }
        *(float4*)cp = *(const float4*)r;
    }
}

// ---------------- flash attention: block = (b,h, 256-query tile) --------------
// One thread per query. K/V staged in LDS in 64-row tiles (coalesced float4
// global loads). LDS reads are wave-broadcast (all lanes same K/V row).
__global__ __launch_bounds__(256) void k_attn(const float* __restrict__ q,
                                              const float* __restrict__ k,
                                              const float* __restrict__ v,
                                              float* __restrict__ o) {
    __shared__ float Ks[64][36];   // +4 pad: spreads staging writes over banks
    __shared__ float Vs[64][36];
    int tid = threadIdx.x;
    int bh = blockIdx.y;            // 0..127
    int b = bh >> 4, h = bh & 15;
    int q0 = blockIdx.x * 256;
    int t = q0 + tid;

    const float* qrow = q + (size_t)(b * TT + t) * CC + h * HSZ;
    float qr[32];
#pragma unroll
    for (int d = 0; d < 32; d += 4) {
        float4 qq = *(const float4*)(qrow + d);
        qr[d] = qq.x; qr[d + 1] = qq.y; qr[d + 2] = qq.z; qr[d + 3] = qq.w;
    }
    const float scale = 0.1767766952966369f;  // 1/sqrt(32)
    float m = -1e30f, l = 0.f;
    float acc[32];
#pragma unroll
    for (int d = 0; d < 32; d++) acc[d] = 0.f;

    int s_end = q0 + 256;           // block-uniform causal bound
    for (int s0 = 0; s0 < s_end; s0 += 64) {
        __syncthreads();
        // stage K/V tile: 64 rows x 32 floats each; 512 float4 per tensor,
        // 256 threads -> 2 float4 each, coalesced in 8-float4 row segments.
#pragma unroll
        for (int i = 0; i < 2; i++) {
            int j = i * 256 + tid;
            int r = j >> 3, d4 = (j & 7) * 4;
            size_t g = (size_t)(b * TT + s0 + r) * CC + h * HSZ + d4;
            *(float4*)(&Ks[r][d4]) = *(const float4*)(k + g);
            *(float4*)(&Vs[r][d4]) = *(const float4*)(v + g);
        }
        __syncthreads();
        int smax = t - s0;
        if (smax > 63) smax = 63;
        for (int ss = 0; ss <= smax; ss++) {
            float dot = 0.f;
#pragma unroll
            for (int d = 0; d < 32; d += 4) {
                float4 kk = *(const float4*)(&Ks[ss][d]);
                dot += qr[d] * kk.x + qr[d + 1] * kk.y
                     + qr[d + 2] * kk.z + qr[d + 3] * kk.w;
            }
            float xv = dot * scale;
            float mn = fmaxf(m, xv);
            float corr = __expf(m - mn);
            float p = __expf(xv - mn);
            l = l * corr + p;
            m = mn;
#pragma unroll
            for (int d = 0; d < 32; d += 4) {
                float4 vv = *(const float4*)(&Vs[ss][d]);
                acc[d]     = acc[d]     * corr + p * vv.x;
                acc[d + 1] = acc[d + 1] * corr + p * vv.y;
                acc[d + 2] = acc[d + 2] * corr + p * vv.z;
                acc[d + 3] = acc[d + 3] * corr + p * vv.w;
            }
        }
    }
    float invl = 1.f / l;
    float* orow = o + (size_t)(b * TT + t) * CC + h * HSZ;
#pragma unroll
    for (int d = 0; d < 32; d += 4) {
        float4 r;
        r.x = acc[d] * invl; r.y = acc[d + 1] * invl;
        r.z = acc[d + 2] * invl; r.w = acc[d + 3] * invl;
        *(float4*)(orow + d) = r;
    }
}

// ---------------- loss ----------------
__global__ void k_zero(float* p) { *p = 0.f; }

__global__ __launch_bounds__(256) void k_loss(const float* __restrict__ logits,
                                              const int* __restrict__ targets,
                                              float* __restrict__ loss) {
    int row = blockIdx.x;
    const float* lr = logits + (size_t)row * VV;
    int tid = threadIdx.x;
    float m = -1e30f, s = 0.f;
    for (int j = tid * 4; j < VV; j += 1024) {
        float4 xv = *(const float4*)(lr + j);
        float xs[4] = {xv.x, xv.y, xv.z, xv.w};
#pragma unroll
        for (int u = 0; u < 4; u++) {
            float mn = fmaxf(m, xs[u]);
            s = s * __expf(m - mn) + __expf(xs[u] - mn);
            m = mn;
        }
    }
#pragma unroll
    for (int off = 32; off; off >>= 1) {
        float m2 = __shfl_xor(m, off);
        float s2 = __shfl_xor(s, off);
        float mn = fmaxf(m, m2);
        s = s * __expf(m - mn) + s2 * __expf(m2 - mn);
        m = mn;
    }
    __shared__ float sm[4], ss[4];
    int wave = tid >> 6, lane = tid & 63;
    if (lane == 0) { sm[wave] = m; ss[wave] = s; }
    __syncthreads();
    if (tid == 0) {
        float M = fmaxf(fmaxf(sm[0], sm[1]), fmaxf(sm[2], sm[3]));
        float S = ss[0] * __expf(sm[0] - M) + ss[1] * __expf(sm[1] - M)
                + ss[2] * __expf(sm[2] - M) + ss[3] * __expf(sm[3] - M);
        float lt = lr[targets[row]];
        atomicAdd(loss, -(lt - M - logf(S)) * (1.0f / (float)MROWS));
    }
}

// ---------------- orchestration ----------------
extern "C" void kernel_launch(void* const* d_in, const int* in_sizes, int n_in,
                              void* d_out, int out_size, void* d_ws, size_t ws_size,
                              hipStream_t stream) {
    const int*   idx   = (const int*)d_in[0];
    const int*   idxl  = (const int*)d_in[1];
    const int*   tgt   = (const int*)d_in[2];
    const float* tok   = (const float*)d_in[3];
    const float* pos   = (const float*)d_in[4];
    const float* lab   = (const float*)d_in[5];
    const float* Wq    = (const float*)d_in[6];
    const float* Wk    = (const float*)d_in[7];
    const float* Wv    = (const float*)d_in[8];
    const float* Wo    = (const float*)d_in[9];
    const float* bo    = (const float*)d_in[10];
    const float* ln1g  = (const float*)d_in[11];
    const float* ln1b  = (const float*)d_in[12];
    const float* W1    = (const float*)d_in[13];
    const float* b1    = (const float*)d_in[14];
    const float* W2    = (const float*)d_in[15];
    const float* b2    = (const float*)d_in[16];
    const float* ln2g  = (const float*)d_in[17];
    const float* ln2b  = (const float*)d_in[18];
    const float* lnfg  = (const float*)d_in[19];
    const float* lnfb  = (const float*)d_in[20];
    const float* Wlm   = (const float*)d_in[21];
    const float* blm   = (const float*)d_in[22];
    float* out = (float*)d_out;
    float* ws  = (float*)d_ws;

    const size_t NTOK = (size_t)MROWS * CC;   // 4,194,304
    float* x  = ws;
    float* h  = x  + NTOK;
    float* qb = h  + NTOK;
    float* kb = qb + NTOK;
    float* vb = kb + NTOK;
    float* ob = vb + NTOK;
    float* ff = ob + NTOK;                    // 8192*2048

    dim3 blk(256);
    dim3 gs_sq(CC / 64, MROWS / 64);          // 8  x 128
    dim3 gs_ff(FFD / 64, MROWS / 64);         // 32 x 128
    dim3 gs_lm(VV / 64, MROWS / 64);          // 128 x 128
    dim3 gs_at(TT / 256, BBATCH * NH);        // 4 x 128

    k_embed<<<MROWS, 128, 0, stream>>>(idx, idxl, tok, pos, lab, x);

    for (int l = 0; l < NL; l++) {
        k_ln<<<MROWS / 4, blk, 0, stream>>>(x, ln1g + l * CC, ln1b + l * CC, h);
        const size_t wqkv = (size_t)l * NH * CC * HSZ;
        k_gemm<0, 0, 1><<<gs_sq, blk, 0, stream>>>(h, Wq + wqkv, nullptr, qb, MROWS, CC, CC);
        k_gemm<0, 0, 1><<<gs_sq, blk, 0, stream>>>(h, Wk + wqkv, nullptr, kb, MROWS, CC, CC);
        k_gemm<0, 0, 1><<<gs_sq, blk, 0, stream>>>(h, Wv + wqkv, nullptr, vb, MROWS, CC, CC);
        k_attn<<<gs_at, blk, 0, stream>>>(qb, kb, vb, ob);
        k_gemm<0, 1, 0><<<gs_sq, blk, 0, stream>>>(ob, Wo + (size_t)l * CC * CC,
                                                   bo + l * CC, x, MROWS, CC, CC);
        k_ln<<<MROWS / 4, blk, 0, stream>>>(x, ln2g + l * CC, ln2b + l * CC, h);
        k_gemm<1, 0, 0><<<gs_ff, blk, 0, stream>>>(h, W1 + (size_t)l * CC * FFD,
                                                   b1 + l * FFD, ff, MROWS, FFD, CC);
        k_gemm<0, 1, 0><<<gs_sq, blk, 0, stream>>>(ff, W2 + (size_t)l * FFD * CC,
                                                   b2 + l * CC, x, MROWS, CC, FFD);
    }

    k_ln<<<MROWS / 4, blk, 0, stream>>>(x, lnfg, lnfb, h);
    k_gemm<0, 0, 0><<<gs_lm, blk, 0, stream>>>(h, Wlm, blm, out, MROWS, VV, CC);

    float* loss_p = out + (size_t)MROWS * VV;
    k_zero<<<1, 1, 0, stream>>>(loss_p);
    k_loss<<<MROWS, blk, 0, stream>>>(out, tgt, loss_p);
}